// Round 13
// baseline (59.207 us; speedup 1.0000x reference)
//
#include <hip/hip_runtime.h>

typedef float floatx3 __attribute__((ext_vector_type(3), aligned(4)));

// SMPL 24-joint tree ancestor tables (root-clipped to 0; root's bone offset is
// 0 so clipped slots contribute exactly 0).
// cA1 = parent, cA2 = 2nd ancestor, cA4 = 4th ancestor.
// Lane j pair-sum P = v[j]+v[a1]; P2 = P + P[a2] covers 4 nodes; P4 = P2 +
// P2[a4] covers 8 — exact for every chain (max 8 non-root nodes).
__device__ __constant__ int cA1[24] = {0,0,0,0,1,2,3,4,5,6,7,8,9,9,9,12,13,14,16,17,18,19,20,21};
__device__ __constant__ int cA2[24] = {0,0,0,0,0,0,0,1,2,3,4,5,6,6,6,9,9,9,13,14,16,17,18,19};
__device__ __constant__ int cA4[24] = {0,0,0,0,0,0,0,0,0,0,0,0,0,0,0,3,3,3,6,6,9,9,13,14};

#define ITERS 16   // batches per 32-lane group per block

__device__ __forceinline__ void qrot_acc(const float4 q,
                                         const float ox, const float oy, const float oz,
                                         float& vx, float& vy, float& vz) {
    const float w = q.x, x = q.y, y = q.z, z = q.w;
    vx += (1.f - 2.f * (y * y + z * z)) * ox + (2.f * (x * y - z * w)) * oy + (2.f * (x * z + y * w)) * oz;
    vy += (2.f * (x * y + z * w)) * ox + (1.f - 2.f * (x * x + z * z)) * oy + (2.f * (y * z - x * w)) * oz;
    vz += (2.f * (x * z - y * w)) * ox + (2.f * (y * z + x * w)) * oy + (1.f - 2.f * (x * x + y * y)) * oz;
}

__global__ __launch_bounds__(256, 8) void fk_kernel(
    const float* __restrict__ rot,      // [B, 24, 4]
    const float* __restrict__ skel,     // [24, 3]
    float* __restrict__ out,            // [B, 24, 3]
    int B)
{
    const int tid = threadIdx.x;
    const int j   = tid & 31;           // joint lane within 32-lane group
    const int grp = tid >> 5;           // 0..7 batch-groups per block
    const int jc  = (j < 24) ? j : 0;

    const int a1 = cA1[jc], a2 = cA2[jc], a4 = cA4[jc];

    // Loop-invariant rest-pose bone offsets for self and parent.
    const float sJx = skel[jc * 3 + 0], sJy = skel[jc * 3 + 1], sJz = skel[jc * 3 + 2];
    const float s1x = skel[a1 * 3 + 0], s1y = skel[a1 * 3 + 1], s1z = skel[a1 * 3 + 2];
    const float s2x = skel[a2 * 3 + 0], s2y = skel[a2 * 3 + 1], s2z = skel[a2 * 3 + 2];
    const float oSx = sJx - s1x, oSy = sJy - s1y, oSz = sJz - s1z;
    const float oPx = s1x - s2x, oPy = s1y - s2y, oPz = s1z - s2z;

    const float4* __restrict__ rot4 = reinterpret_cast<const float4*>(rot);

    const int base = blockIdx.x * (8 * ITERS);   // first batch of this block

#pragma unroll 4
    for (int it = 0; it < ITERS; ++it) {
        const int b = base + it * 8 + grp;
        if (b < B) {
            const size_t b24 = (size_t)b * 24;
            const float4 qS = rot4[b24 + jc];    // self quat
            const float4 qP = rot4[b24 + a1];    // parent quat (same 384B block)

            // Local pair sum v[j] + v[a1].
            float vx = 0.f, vy = 0.f, vz = 0.f;
            qrot_acc(qS, oSx, oSy, oSz, vx, vy, vz);
            qrot_acc(qP, oPx, oPy, oPz, vx, vy, vz);

            // Two pointer jumps: 4-node then 8-node coverage (exact).
            const float x2 = vx + __shfl(vx, a2, 32);
            const float y2 = vy + __shfl(vy, a2, 32);
            const float z2 = vz + __shfl(vz, a2, 32);

            const float cx = x2 + __shfl(x2, a4, 32);
            const float cy = y2 + __shfl(y2, a4, 32);
            const float cz = z2 + __shfl(z2, a4, 32);

            // Direct per-lane dwordx3 store: 24 lanes x contiguous 12B = dense
            // 288B per group, full 64B lines per wave instruction. Nontemporal
            // so the output bypasses L2/L3 and the input stays L3-resident.
            if (j < 24) {
                floatx3 v; v.x = cx; v.y = cy; v.z = cz;
                __builtin_nontemporal_store(
                    v, reinterpret_cast<floatx3*>(out + (size_t)b * 72 + 3 * j));
            }
        }
    }
}

extern "C" void kernel_launch(void* const* d_in, const int* in_sizes, int n_in,
                              void* d_out, int out_size, void* d_ws, size_t ws_size,
                              hipStream_t stream) {
    const float* rot  = (const float*)d_in[0];   // [B, 24, 4] f32
    const float* skel = (const float*)d_in[1];   // [24, 3] f32
    float* out = (float*)d_out;                  // [B, 24, 3] f32

    const int B = in_sizes[0] / (24 * 4);        // 524288
    const int perBlock = 8 * ITERS;              // 128 batches per block
    const int grid = (B + perBlock - 1) / perBlock;   // 4096
    fk_kernel<<<grid, 256, 0, stream>>>(rot, skel, out, B);
}